// Round 14
// baseline (402.284 us; speedup 1.0000x reference)
//
#include <hip/hip_runtime.h>
#include <hip/hip_bf16.h>
#include <math.h>

// ---- problem constants ----
constexpr int Bc   = 32;
constexpr int Nc   = 196;
constexpr int Cc   = 768;
constexpr int Hc   = 12;
constexpr int HDc  = 64;
constexpr int Lc   = 4;
constexpr int DFFc = 3072;
constexpr int NCAT = 2 * Nc;          // 392
constexpr int Mrows = Bc * Nc;        // 6272
constexpr float SCALE_C = 0.03608439182435161f;  // 768^-0.5
constexpr float SCALE_H = 0.125f;                // 64^-0.5
constexpr float LOG2E   = 1.4426950408889634f;

typedef __attribute__((ext_vector_type(8))) short short8;
typedef __attribute__((ext_vector_type(4))) short s16x4;
typedef __attribute__((ext_vector_type(4))) float float4a;
typedef __attribute__((ext_vector_type(4))) _Float16 half4;

// tanh-form GELU (max |err| vs exact ~1e-3; margin is 0.086)
__device__ inline float gelu_fast(float v) {
    float c = v * (0.7978845608028654f + 0.035677408136300125f * v * v);
    float ex = __expf(2.f * c);
    float th = 1.f - 2.f / (ex + 1.f);
    return 0.5f * v * (1.f + th);
}

__device__ inline void store_val(float* p, float v) { *p = v; }
__device__ inline void store_val(__hip_bfloat16* p, float v) { *p = __float2bfloat16(v); }

__device__ inline void gload16(const void* g, void* l) {
    __builtin_amdgcn_global_load_lds(
        (const __attribute__((address_space(1))) void*)g,
        (__attribute__((address_space(3))) void*)l, 16, 0, 0);
}

// =====================================================================
// Latent scores: one WAVE per (b,j), all 4 latents at once.
// =====================================================================
__global__ __launch_bounds__(256) void lat_scores_ker(
    const float* __restrict__ x, const float* __restrict__ y,
    const float* __restrict__ lat, float* __restrict__ scores)
{
    int wglobal = blockIdx.x * 4 + (threadIdx.x >> 6);
    int lane = threadIdx.x & 63;
    int b = wglobal / NCAT, j = wglobal % NCAT;
    const float* row = (j < Nc) ? x + ((size_t)b * Nc + j) * Cc
                                : y + ((size_t)b * Nc + (j - Nc)) * Cc;
    float a0 = 0.f, a1 = 0.f, a2 = 0.f, a3 = 0.f;
    for (int c = lane; c < Cc; c += 64) {
        float rv = row[c];
        a0 += rv * lat[c];
        a1 += rv * lat[Cc + c];
        a2 += rv * lat[2 * Cc + c];
        a3 += rv * lat[3 * Cc + c];
    }
    #pragma unroll
    for (int o = 32; o; o >>= 1) {
        a0 += __shfl_xor(a0, o);
        a1 += __shfl_xor(a1, o);
        a2 += __shfl_xor(a2, o);
        a3 += __shfl_xor(a3, o);
    }
    if (lane == 0) {
        float* sb = scores + (size_t)b * Lc * NCAT + j;
        sb[0 * NCAT] = a0 * SCALE_C;
        sb[1 * NCAT] = a1 * SCALE_C;
        sb[2 * NCAT] = a2 * SCALE_C;
        sb[3 * NCAT] = a3 * SCALE_C;
    }
}

// =====================================================================
// softmax(scores) (in-LDS, wave w -> latent w) + fused = probs @ concat.
// grid (Bc, 12): 64-col chunk.
// =====================================================================
__global__ __launch_bounds__(256) void lat_fused_ker(
    const float* __restrict__ x, const float* __restrict__ y,
    const float* __restrict__ scores, float* __restrict__ fused)
{
    int b = blockIdx.x, chunk = blockIdx.y;
    int t = threadIdx.x;
    __shared__ float p[Lc][NCAT];
    for (int idx = t; idx < Lc * NCAT; idx += 256)
        (&p[0][0])[idx] = scores[(size_t)b * Lc * NCAT + idx];
    __syncthreads();
    int w = t >> 6, lane = t & 63;
    {   // wave w softmaxes latent row w (redundant across chunks; cheap)
        float m = -INFINITY;
        for (int j = lane; j < NCAT; j += 64) m = fmaxf(m, p[w][j]);
        #pragma unroll
        for (int o = 32; o; o >>= 1) m = fmaxf(m, __shfl_xor(m, o));
        float sum = 0.f;
        for (int j = lane; j < NCAT; j += 64) {
            float e = expf(p[w][j] - m);
            p[w][j] = e;
            sum += e;
        }
        #pragma unroll
        for (int o = 32; o; o >>= 1) sum += __shfl_xor(sum, o);
        float inv = 1.f / sum;
        for (int j = lane; j < NCAT; j += 64) p[w][j] *= inv;
    }
    __syncthreads();

    int l = w;
    int c = chunk * 64 + lane;
    float acc0 = 0.f, acc1 = 0.f;
    for (int j = 0; j < Nc; j += 2) {
        const float* r0 = x + ((size_t)b * Nc + j) * Cc;
        acc0 += p[l][j] * r0[c];
        acc1 += p[l][j + 1] * r0[Cc + c];
    }
    for (int j = 0; j < Nc; j += 2) {
        const float* r0 = y + ((size_t)b * Nc + j) * Cc;
        acc0 += p[l][Nc + j] * r0[c];
        acc1 += p[l][Nc + j + 1] * r0[Cc + c];
    }
    fused[(size_t)b * Lc * Cc + l * Cc + c] = acc0 + acc1;
}

// =====================================================================
// inject (fallback, no LN): out = src + scale * sdpa(src, fused, fused)
// =====================================================================
__global__ __launch_bounds__(256) void inject_ker(
    const float* __restrict__ x, const float* __restrict__ y,
    const float* __restrict__ fused,
    const float* __restrict__ scale_a, const float* __restrict__ scale_v,
    float* __restrict__ out)
{
    int gid = blockIdx.x;
    int st = gid / Mrows;
    int bn = gid % Mrows;
    int b = bn / Nc;
    const float* src = st ? y : x;
    float scale = st ? scale_v[0] : scale_a[0];
    float* dst = out + (size_t)st * Mrows * Cc;
    const float* f = fused + (size_t)b * Lc * Cc;
    const float* row = src + (size_t)bn * Cc;

    __shared__ float sc[4];
    int w = threadIdx.x >> 6, lane = threadIdx.x & 63;
    float partial = 0.f;
    for (int c = lane; c < Cc; c += 64) partial += row[c] * f[w * Cc + c];
    #pragma unroll
    for (int o = 32; o; o >>= 1) partial += __shfl_xor(partial, o);
    if (lane == 0) sc[w] = partial * SCALE_C;
    __syncthreads();

    float s0 = sc[0], s1 = sc[1], s2 = sc[2], s3 = sc[3];
    float m = fmaxf(fmaxf(s0, s1), fmaxf(s2, s3));
    float e0 = expf(s0 - m), e1 = expf(s1 - m), e2 = expf(s2 - m), e3 = expf(s3 - m);
    float inv = 1.f / (e0 + e1 + e2 + e3);
    e0 *= inv; e1 *= inv; e2 *= inv; e3 *= inv;

    for (int c = threadIdx.x; c < Cc; c += 256) {
        float v = e0 * f[c] + e1 * f[Cc + c] + e2 * f[2 * Cc + c] + e3 * f[3 * Cc + c];
        dst[(size_t)bn * Cc + c] = row[c] + scale * v;
    }
}

// =====================================================================
// inject + LN1 fused: u = src + scale*sdpa; out=u (fp32); lnout=LN(u) bf16
// =====================================================================
__global__ __launch_bounds__(256) void inject_ln_ker(
    const float* __restrict__ x, const float* __restrict__ y,
    const float* __restrict__ fusedb,
    const float* __restrict__ scale_a, const float* __restrict__ scale_v,
    const float* __restrict__ ga, const float* __restrict__ ba,
    const float* __restrict__ gv, const float* __restrict__ bv,
    float* __restrict__ out, __hip_bfloat16* __restrict__ lnout, size_t lnz)
{
    int gid = blockIdx.x;
    int st = gid / Mrows;
    int bn = gid % Mrows;
    int b = bn / Nc;
    const float* src = st ? y : x;
    float scale = st ? scale_v[0] : scale_a[0];
    const float* g  = st ? gv : ga;
    const float* bb = st ? bv : ba;
    float* dst = out + (size_t)st * Mrows * Cc + (size_t)bn * Cc;
    __hip_bfloat16* lno = lnout + (size_t)st * lnz + (size_t)bn * Cc;
    const float* f = fusedb + (size_t)b * Lc * Cc;
    const float* row = src + (size_t)bn * Cc;

    __shared__ float sc[4];
    __shared__ float red[4];
    int t = threadIdx.x;
    int w = t >> 6, lane = t & 63;
    float partial = 0.f;
    for (int c = lane; c < Cc; c += 64) partial += row[c] * f[w * Cc + c];
    #pragma unroll
    for (int o = 32; o; o >>= 1) partial += __shfl_xor(partial, o);
    if (lane == 0) sc[w] = partial * SCALE_C;
    __syncthreads();

    float s0 = sc[0], s1 = sc[1], s2 = sc[2], s3 = sc[3];
    float m = fmaxf(fmaxf(s0, s1), fmaxf(s2, s3));
    float e0 = expf(s0 - m), e1 = expf(s1 - m), e2 = expf(s2 - m), e3 = expf(s3 - m);
    float inv = 1.f / (e0 + e1 + e2 + e3);
    e0 *= inv; e1 *= inv; e2 *= inv; e3 *= inv;

    float u[3];
    float s = 0.f;
    #pragma unroll
    for (int k = 0; k < 3; ++k) {
        int c = t + 256 * k;
        float v = e0 * f[c] + e1 * f[Cc + c] + e2 * f[2 * Cc + c] + e3 * f[3 * Cc + c];
        u[k] = row[c] + scale * v;
        s += u[k];
    }
    #pragma unroll
    for (int o = 32; o; o >>= 1) s += __shfl_xor(s, o);
    if (lane == 0) red[w] = s;
    __syncthreads();
    float mean = (red[0] + red[1] + red[2] + red[3]) * (1.f / Cc);

    float vs = 0.f;
    #pragma unroll
    for (int k = 0; k < 3; ++k) { float d = u[k] - mean; vs += d * d; }
    #pragma unroll
    for (int o = 32; o; o >>= 1) vs += __shfl_xor(vs, o);
    __syncthreads();
    if (lane == 0) red[w] = vs;
    __syncthreads();
    float var = (red[0] + red[1] + red[2] + red[3]) * (1.f / Cc);
    float rinv = 1.f / sqrtf(var + 1e-6f);

    #pragma unroll
    for (int k = 0; k < 3; ++k) {
        int c = t + 256 * k;
        dst[c] = u[k];
        lno[c] = __float2bfloat16((u[k] - mean) * rinv * g[c] + bb[c]);
    }
}

// =====================================================================
// LayerNorm -> bf16, float4-vectorized, values kept in registers.
// =====================================================================
__global__ __launch_bounds__(256) void ln_ker(
    const float* __restrict__ in, size_t inz,
    const float* __restrict__ g0, const float* __restrict__ b0,
    const float* __restrict__ g1, const float* __restrict__ b1,
    __hip_bfloat16* __restrict__ out, size_t outz)
{
    int z = blockIdx.z;
    const float* g = z ? g1 : g0;
    const float* bb = z ? b1 : b0;
    in += (size_t)z * inz; out += (size_t)z * outz;

    int row = blockIdx.x;
    __shared__ float red[4];
    __shared__ float red2[4];
    const float* r = in + (size_t)row * Cc;
    int t = threadIdx.x;
    int w = t >> 6, lane = t & 63;
    bool act = t < 192;

    float4 v = act ? *reinterpret_cast<const float4*>(r + t * 4)
                   : make_float4(0.f, 0.f, 0.f, 0.f);
    float s = v.x + v.y + v.z + v.w;
    #pragma unroll
    for (int o = 32; o; o >>= 1) s += __shfl_xor(s, o);
    if (lane == 0) red[w] = s;
    __syncthreads();
    float mean = (red[0] + red[1] + red[2] + red[3]) * (1.f / Cc);

    float d0 = v.x - mean, d1 = v.y - mean, d2 = v.z - mean, d3 = v.w - mean;
    float vs = act ? (d0 * d0 + d1 * d1 + d2 * d2 + d3 * d3) : 0.f;
    #pragma unroll
    for (int o = 32; o; o >>= 1) vs += __shfl_xor(vs, o);
    if (lane == 0) red2[w] = vs;
    __syncthreads();
    float var = (red2[0] + red2[1] + red2[2] + red2[3]) * (1.f / Cc);
    float inv = 1.f / sqrtf(var + 1e-6f);

    if (act) {
        float4 gv = *reinterpret_cast<const float4*>(g + t * 4);
        float4 bv = *reinterpret_cast<const float4*>(bb + t * 4);
        __hip_bfloat16 tmp[4];
        tmp[0] = __float2bfloat16(d0 * inv * gv.x + bv.x);
        tmp[1] = __float2bfloat16(d1 * inv * gv.y + bv.y);
        tmp[2] = __float2bfloat16(d2 * inv * gv.z + bv.z);
        tmp[3] = __float2bfloat16(d3 * inv * gv.w + bv.w);
        *reinterpret_cast<s16x4*>(out + (size_t)row * Cc + t * 4) =
            *reinterpret_cast<const s16x4*>(tmp);
    }
}

// =====================================================================
// All 8 weight transposes, float4-vectorized. grid (6912, 1, 2).
// Load: thread (r = t>>3, c4 = (t&7)*4) pulls one float4.
// Store: thread (rn = t>>3, k4 = (t&7)*4) writes one s16x4 (4 k's).
// =====================================================================
struct WArgs {
    const float* src[8];
    __hip_bfloat16* dst[8];
};

__global__ __launch_bounds__(256) void wcast_all_ker(WArgs wa)
{
    int z = blockIdx.z;
    int bx = blockIdx.x;
    int which, tile, K_, N_;
    if (bx < 1728)      { which = 0; tile = bx;        K_ = 768;  N_ = 2304; }
    else if (bx < 2304) { which = 1; tile = bx - 1728; K_ = 768;  N_ = 768;  }
    else if (bx < 4608) { which = 2; tile = bx - 2304; K_ = 768;  N_ = 3072; }
    else                { which = 3; tile = bx - 4608; K_ = 3072; N_ = 768;  }
    const float* W = wa.src[z * 4 + which];
    __hip_bfloat16* WT = wa.dst[z * 4 + which];
    int ntx = N_ >> 5;
    int n0 = (tile % ntx) * 32, k0 = (tile / ntx) * 32;

    __shared__ float tilebuf[32][33];
    int t = threadIdx.x;
    int r = t >> 3, c4 = (t & 7) * 4;
    float4 v = *reinterpret_cast<const float4*>(&W[(size_t)(k0 + r) * N_ + n0 + c4]);
    tilebuf[r][c4 + 0] = v.x;
    tilebuf[r][c4 + 1] = v.y;
    tilebuf[r][c4 + 2] = v.z;
    tilebuf[r][c4 + 3] = v.w;
    __syncthreads();

    int rn = t >> 3, k4 = (t & 7) * 4;
    __hip_bfloat16 tmp[4];
    #pragma unroll
    for (int i = 0; i < 4; ++i)
        tmp[i] = __float2bfloat16(tilebuf[k4 + i][rn]);
    *reinterpret_cast<s16x4*>(&WT[(size_t)(n0 + rn) * K_ + k0 + k4]) =
        *reinterpret_cast<const s16x4*>(tmp);
}

// =====================================================================
// bf16 MFMA GEMM, 128x128 tile: round-7 verbatim — BK=64 single-buffered
// (32 KB LDS), two __syncthreads per K-tile, (256,2), XCD-chunk swizzle.
// Used for qkv + fc1 (large grids).
// =====================================================================
template <int EPI, typename OutT>
__global__ __launch_bounds__(256, 2) void gemm_bf16_ker(
    const __hip_bfloat16* __restrict__ A, size_t Az,
    const __hip_bfloat16* __restrict__ BT, size_t BTz,
    const float* __restrict__ bias0, const float* __restrict__ bias1,
    const float* __restrict__ res, size_t resz,
    OutT* __restrict__ out, size_t outz,
    int M_, int N_, int K_)
{
    const int gx = gridDim.x, gy = gridDim.y;
    const long T = (long)gx * gy * gridDim.z;
    long iflat = blockIdx.x + (long)gx * (blockIdx.y + (long)gy * blockIdx.z);
    long q = T >> 3, r = T & 7;
    long xcd = iflat & 7, jj = iflat >> 3;
    long tt = (xcd < r ? xcd * (q + 1) : r * (q + 1) + (xcd - r) * q) + jj;
    const int bx = (int)(tt % gx);
    const int by = (int)((tt / gx) % gy);
    const int z  = (int)(tt / ((long)gx * gy));

    A += (size_t)z * Az;
    BT += (size_t)z * BTz;
    const float* bias = z ? bias1 : bias0;
    res += (size_t)z * resz;
    out += (size_t)z * outz;

    __shared__ short As[128 * 64];
    __shared__ short Bs[128 * 64];
    const int t = threadIdx.x;
    const int wid = t >> 6, lane = t & 63;
    const int row0 = by * 128, col0 = bx * 128;
    const int wr = (wid >> 1) * 64, wc = (wid & 1) * 64;

    const __hip_bfloat16* aSrc[4];
    const __hip_bfloat16* bSrc[4];
    int ldsOff[4];
    #pragma unroll
    for (int ii = 0; ii < 4; ++ii) {
        int f = wid * 1024 + ii * 4096 + lane * 16;
        int rw = f >> 7;
        int us = ((f >> 4) & 7) ^ (rw & 7);
        aSrc[ii] = A + (size_t)(row0 + rw) * K_ + us * 8;
        bSrc[ii] = BT + (size_t)(col0 + rw) * K_ + us * 8;
        ldsOff[ii] = (wid * 1024 + ii * 4096) >> 1;
    }

    const int fr = lane & 15;
    const int ku = lane >> 4;
    int rlA[4], rlB[4];
    #pragma unroll
    for (int m = 0; m < 4; ++m) {
        rlA[m] = wr + m * 16 + fr;
        rlB[m] = wc + m * 16 + fr;
    }

    float4a acc[4][4];
    #pragma unroll
    for (int m = 0; m < 4; ++m)
        #pragma unroll
        for (int n = 0; n < 4; ++n)
            acc[m][n] = (float4a)0.f;

    for (int kt = 0; kt < K_; kt += 64) {
        #pragma unroll
        for (int ii = 0; ii < 4; ++ii) {
            gload16(aSrc[ii] + kt, As + ldsOff[ii]);
            gload16(bSrc[ii] + kt, Bs + ldsOff[ii]);
        }
        __syncthreads();

        #pragma unroll
        for (int s = 0; s < 2; ++s) {
            short8 af[4], bf8[4];
            #pragma unroll
            for (int m = 0; m < 4; ++m) {
                int u = (s * 4 + ku) ^ (rlA[m] & 7);
                af[m] = *(const short8*)(As + rlA[m] * 64 + u * 8);
            }
            #pragma unroll
            for (int n = 0; n < 4; ++n) {
                int u = (s * 4 + ku) ^ (rlB[n] & 7);
                bf8[n] = *(const short8*)(Bs + rlB[n] * 64 + u * 8);
            }
            #pragma unroll
            for (int m = 0; m < 4; ++m)
                #pragma unroll
                for (int n = 0; n < 4; ++n)
                    acc[m][n] = __builtin_amdgcn_mfma_f32_16x16x32_bf16(
                        af[m], bf8[n], acc[m][n], 0, 0, 0);
        }
        __syncthreads();
    }

    const int fq = lane >> 4;
    #pragma unroll
    for (int m = 0; m < 4; ++m) {
        #pragma unroll
        for (int n = 0; n < 4; ++n) {
            int col = col0 + wc + n * 16 + fr;
            float b = bias[col];
            #pragma unroll
            for (int j = 0; j < 4; ++j) {
                int row = row0 + wr + m * 16 + fq * 4 + j;
                float v = acc[m][n][j] + b;
                if (EPI == 1) v = gelu_fast(v);
                if (EPI == 2) v += res[(size_t)row * N_ + col];
                store_val(out + (size_t)row * N_ + col, v);
            }
        }
    }
}

// =====================================================================
// bf16 MFMA GEMM, 64x128 tile (BM=64): doubles the block count for the
// grid-starved proj/fc2 shapes (588 -> 1176 blocks). 24 KB LDS.
// Wave w owns output [0..63] x [w*32 .. w*32+31] (acc 4x2).
// Same staging/swizzle formulas as the verified 128-tile kernel.
// =====================================================================
template <int EPI, typename OutT>
__global__ __launch_bounds__(256, 2) void gemm64_bf16_ker(
    const __hip_bfloat16* __restrict__ A, size_t Az,
    const __hip_bfloat16* __restrict__ BT, size_t BTz,
    const float* __restrict__ bias0, const float* __restrict__ bias1,
    const float* __restrict__ res, size_t resz,
    OutT* __restrict__ out, size_t outz,
    int M_, int N_, int K_)
{
    const int gx = gridDim.x, gy = gridDim.y;
    const long T = (long)gx * gy * gridDim.z;
    long iflat = blockIdx.x + (long)gx * (blockIdx.y + (long)gy * blockIdx.z);
    long q = T >> 3, r = T & 7;
    long xcd = iflat & 7, jj = iflat >> 3;
    long tt = (xcd < r ? xcd * (q + 1) : r * (q + 1) + (xcd - r) * q) + jj;
    const int bx = (int)(tt % gx);
    const int by = (int)((tt / gx) % gy);
    const int z  = (int)(tt / ((long)gx * gy));

    A += (size_t)z * Az;
    BT += (size_t)z * BTz;
    const float* bias = z ? bias1 : bias0;
    res += (size_t)z * resz;
    out += (size_t)z * outz;

    __shared__ short As[64 * 64];     // 8 KB
    __shared__ short Bs[128 * 64];    // 16 KB
    const int t = threadIdx.x;
    const int wid = t >> 6, lane = t & 63;
    const int row0 = by * 64, col0 = bx * 128;
    const int wc = wid * 32;

    // A staging: 2 issues/thread cover 8 KB; B: 4 issues cover 16 KB.
    const __hip_bfloat16* aSrc[2];
    const __hip_bfloat16* bSrc[4];
    int ldsOffA[2], ldsOffB[4];
    #pragma unroll
    for (int ii = 0; ii < 2; ++ii) {
        int f = wid * 1024 + ii * 4096 + lane * 16;
        int rw = f >> 7;
        int us = ((f >> 4) & 7) ^ (rw & 7);
        aSrc[ii] = A + (size_t)(row0 + rw) * K_ + us * 8;
        ldsOffA[ii] = (wid * 1024 + ii * 4096) >> 1;
    }
    #pragma unroll
    for (int ii = 0; ii < 4; ++ii) {
        int f = wid * 1024 + ii * 4096 + lane * 16;
        int rw = f >> 7;
        int us = ((f >> 4) & 7) ^ (rw & 7);
        bSrc[ii] = BT + (size_t)(col0 + rw) * K_ + us * 8;
        ldsOffB[ii] = (wid * 1024 + ii * 4096) >> 1;
    }

    const int fr = lane & 15;
    const int ku = lane >> 4;
    int rlA[4], rlB[2];
    #pragma unroll
    for (int m = 0; m < 4; ++m) rlA[m] = m * 16 + fr;
    #pragma unroll
    for (int n = 0; n < 2; ++n) rlB[n] = wc + n * 16 + fr;

    float4a acc[4][2];
    #pragma unroll
    for (int m = 0; m < 4; ++m)
        #pragma unroll
        for (int n = 0; n < 2; ++n)
            acc[m][n] = (float4a)0.f;

    for (int kt = 0; kt < K_; kt += 64) {
        #pragma unroll
        for (int ii = 0; ii < 2; ++ii)
            gload16(aSrc[ii] + kt, As + ldsOffA[ii]);
        #pragma unroll
        for (int ii = 0; ii < 4; ++ii)
            gload16(bSrc[ii] + kt, Bs + ldsOffB[ii]);
        __syncthreads();

        #pragma unroll
        for (int s = 0; s < 2; ++s) {
            short8 af[4], bf8[2];
            #pragma unroll
            for (int m = 0; m < 4; ++m) {
                int u = (s * 4 + ku) ^ (rlA[m] & 7);
                af[m] = *(const short8*)(As + rlA[m] * 64 + u * 8);
            }
            #pragma unroll
            for (int n = 0; n < 2; ++n) {
                int u = (s * 4 + ku) ^ (rlB[n] & 7);
                bf8[n] = *(const short8*)(Bs + rlB[n] * 64 + u * 8);
            }
            #pragma unroll
            for (int m = 0; m < 4; ++m)
                #pragma unroll
                for (int n = 0; n < 2; ++n)
                    acc[m][n] = __builtin_amdgcn_mfma_f32_16x16x32_bf16(
                        af[m], bf8[n], acc[m][n], 0, 0, 0);
        }
        __syncthreads();
    }

    const int fq = lane >> 4;
    #pragma unroll
    for (int m = 0; m < 4; ++m) {
        #pragma unroll
        for (int n = 0; n < 2; ++n) {
            int col = col0 + wc + n * 16 + fr;
            float b = bias[col];
            #pragma unroll
            for (int j = 0; j < 4; ++j) {
                int row = row0 + m * 16 + fq * 4 + j;
                float v = acc[m][n][j] + b;
                if (EPI == 1) v = gelu_fast(v);
                if (EPI == 2) v += res[(size_t)row * N_ + col];
                store_val(out + (size_t)row * N_ + col, v);
            }
        }
    }
}

// =====================================================================
// MFMA attention, z-batched. Block per (h, b, z).
// =====================================================================
constexpr int NKT = 13;
constexpr int NQT = 13;
constexpr int NPAD = NKT * 16;   // 208
constexpr int VTS = 216;

__global__ __launch_bounds__(256) void attn_mfma_ker(
    const __hip_bfloat16* __restrict__ qkv, size_t qz,
    __hip_bfloat16* __restrict__ o, size_t oz)
{
    int z = blockIdx.z;
    qkv += (size_t)z * qz;
    o += (size_t)z * oz;

    int h = blockIdx.x, b = blockIdx.y;
    __shared__ short Ks[NPAD * 64];
    __shared__ _Float16 VT[64 * VTS];
    const size_t rs = 3 * Cc;
    const __hip_bfloat16* base = qkv + (size_t)b * Nc * rs + h * HDc;
    const int t = threadIdx.x;

    for (int c = t; c < NPAD * 8; c += 256) {
        int row = c >> 3, u = c & 7;
        int srow = row < Nc ? row : Nc - 1;
        short8 kv = *(const short8*)(base + (size_t)srow * rs + Cc + u * 8);
        *(short8*)(Ks + row * 64 + ((u ^ (row & 7)) << 3)) = kv;
        short8 vv = *(const short8*)(base + (size_t)srow * rs + 2 * Cc + u * 8);
        #pragma unroll
        for (int w = 0; w < 8; ++w) {
            __hip_bfloat16 bvv = ((const __hip_bfloat16*)&vv)[w];
            VT[(u * 8 + w) * VTS + row] = (_Float16)__bfloat162float(bvv);
        }
    }
    __syncthreads();

    const int wv = t >> 6, lane = t & 63;
    const int g = lane >> 4, c16 = lane & 15;
    const float KS = SCALE_H * LOG2E;

    for (int qt = wv; qt < NQT; qt += 4) {
        int qrow = qt * 16 + c16;
        int sq = qrow < Nc ? qrow : Nc - 1;
        const __hip_bfloat16* qb = base + (size_t)sq * rs + g * 8;
        short8 bq0 = *(const short8*)(qb);
        short8 bq1 = *(const short8*)(qb + 32);

        float4a acc[NKT];
        #pragma unroll
        for (int kt = 0; kt < NKT; ++kt) acc[kt] = (float4a)0.f;
        #pragma unroll
        for (int kt = 0; kt < NKT; ++kt) {
            int r = kt * 16 + c16;
            short8 a0 = *(const short8*)(Ks + r * 64 + ((g ^ (r & 7)) << 3));
            short8 a1 = *(const short8*)(Ks + r * 64 + (((4 + g) ^ (r & 7)) << 3));
            acc[kt] = __builtin_amdgcn_mfma_f32_16x16x32_bf16(a0, bq0, acc[kt], 0, 0, 0);
            acc[kt] = __builtin_amdgcn_mfma_f32_16x16x32_bf16(a1, bq1, acc[kt], 0, 0, 0);
        }

        float m = -INFINITY;
        #pragma unroll
        for (int kt = 0; kt < NKT; ++kt) {
            #pragma unroll
            for (int j = 0; j < 4; ++j) {
                int key = kt * 16 + g * 4 + j;
                float v = (key < Nc) ? acc[kt][j] * KS : -INFINITY;
                acc[kt][j] = v;
                m = fmaxf(m, v);
            }
        }
        m = fmaxf(m, __shfl_xor(m, 16));
        m = fmaxf(m, __shfl_xor(m, 32));

        float sum = 0.f;
        half4 pb[NKT];
        #pragma unroll
        for (int kt = 0; kt < NKT; ++kt) {
            #pragma unroll
            for (int j = 0; j < 4; ++j) {
                float e = exp2f(acc[kt][j] - m);
                sum += e;
                pb[kt][j] = (_Float16)e;
            }
        }
        sum += __shfl_xor(sum, 16);
        sum += __shfl_xor(sum, 32);
        float inv = 1.f / sum;

        float4a oa[4];
        #pragma unroll
        for (int dt = 0; dt < 4; ++dt) oa[dt] = (float4a)0.f;
        #pragma unroll
        for (int kt = 0; kt < NKT; ++kt) {
            #pragma unroll
            for (int dt = 0; dt < 4; ++dt) {
                half4 av = *(const half4*)(VT + (size_t)(dt * 16 + c16) * VTS
                                              + kt * 16 + g * 4);
                oa[dt] = __builtin_amdgcn_mfma_f32_16x16x16f16(av, pb[kt], oa[dt], 0, 0, 0);
            }
        }

        if (qrow < Nc) {
            __hip_bfloat16* ob = o + ((size_t)b * Nc + qrow) * Cc + h * HDc;
            #pragma unroll
            for (int dt = 0; dt < 4; ++dt) {
                __hip_bfloat16 tmp[4];
                #pragma unroll
                for (int j = 0; j < 4; ++j)
                    tmp[j] = __float2bfloat16(oa[dt][j] * inv);
                *(s16x4*)(ob + dt * 16 + g * 4) = *(const s16x4*)tmp;
            }
        }
    }
}

// =====================================================================
extern "C" void kernel_launch(void* const* d_in, const int* in_sizes, int n_in,
                              void* d_out, int out_size, void* d_ws, size_t ws_size,
                              hipStream_t stream)
{
    const float* x       = (const float*)d_in[0];
    const float* y       = (const float*)d_in[1];
    const float* latents = (const float*)d_in[2];
    const float* scale_a = (const float*)d_in[3];
    const float* scale_v = (const float*)d_in[4];

    float* out = (float*)d_out;

    constexpr size_t WSTREAM = 7077888;
    constexpr size_t OFF_QKV = 0;
    constexpr size_t OFF_PROJ = 2304 * 768;
    constexpr size_t OFF_FC1 = OFF_PROJ + 768 * 768;
    constexpr size_t OFF_FC2 = OFF_FC1 + 3072 * 768;

    constexpr size_t FRONT = ((size_t)Bc * Lc * NCAT + (size_t)Bc * Lc * Cc) * 4;
    constexpr size_t NEED_BATCH = FRONT
        + 2 * (size_t)Mrows * Cc * 2
        + 2 * (size_t)Mrows * DFFc * 2
        + 2 * WSTREAM * 2;

    float* ws = (float*)d_ws;
    float* scores = ws;
    float* fusedb = scores + (size_t)Bc * Lc * NCAT;

    const bool batched = ws_size >= NEED_BATCH;

    __hip_bfloat16* tbuf = (__hip_bfloat16*)(fusedb + (size_t)Bc * Lc * Cc);
    __hip_bfloat16* big;
    __hip_bfloat16* wT;
    if (batched) {
        big = tbuf + 2 * (size_t)Mrows * Cc;
        wT  = big + 2 * (size_t)Mrows * DFFc;
    } else {
        big = tbuf + (size_t)Mrows * Cc;
        wT  = big + (size_t)Mrows * DFFc;
    }

    // ---- latent bottleneck fusion ----
    lat_scores_ker<<<Bc * NCAT / 4, 256, 0, stream>>>(x, y, latents, scores);
    lat_fused_ker<<<dim3(Bc, 12), 256, 0, stream>>>(x, y, scores, fusedb);

    // ---- weight cast+transpose (all 8 at once) ----
    WArgs wa;
    for (int p = 0; p < 2; ++p) {
        int basei = 5 + 12 * p;
        wa.src[p * 4 + 0] = (const float*)d_in[basei + 2];
        wa.src[p * 4 + 1] = (const float*)d_in[basei + 4];
        wa.src[p * 4 + 2] = (const float*)d_in[basei + 8];
        wa.src[p * 4 + 3] = (const float*)d_in[basei + 10];
        wa.dst[p * 4 + 0] = wT + p * WSTREAM + OFF_QKV;
        wa.dst[p * 4 + 1] = wT + p * WSTREAM + OFF_PROJ;
        wa.dst[p * 4 + 2] = wT + p * WSTREAM + OFF_FC1;
        wa.dst[p * 4 + 3] = wT + p * WSTREAM + OFF_FC2;
    }

    const float* g1[2], *b1[2], *qkvb[2], *projb[2], *g2[2], *b2[2], *fc1b[2], *fc2b[2];
    for (int p = 0; p < 2; ++p) {
        int basei = 5 + 12 * p;
        g1[p]    = (const float*)d_in[basei + 0];
        b1[p]    = (const float*)d_in[basei + 1];
        qkvb[p]  = (const float*)d_in[basei + 3];
        projb[p] = (const float*)d_in[basei + 5];
        g2[p]    = (const float*)d_in[basei + 6];
        b2[p]    = (const float*)d_in[basei + 7];
        fc1b[p]  = (const float*)d_in[basei + 9];
        fc2b[p]  = (const float*)d_in[basei + 11];
    }

    const size_t MC = (size_t)Mrows * Cc;
    const size_t MQKV = (size_t)Mrows * 2304;
    const size_t MFF = (size_t)Mrows * DFFc;

    if (batched) {
        inject_ln_ker<<<2 * Mrows, 256, 0, stream>>>(
            x, y, fusedb, scale_a, scale_v,
            g1[0], b1[0], g1[1], b1[1], out, tbuf, MC);
        wcast_all_ker<<<dim3(6912, 1, 2), 256, 0, stream>>>(wa);
        gemm_bf16_ker<0, __hip_bfloat16><<<dim3(18, 49, 2), 256, 0, stream>>>(
            tbuf, MC, wT + OFF_QKV, WSTREAM, qkvb[0], qkvb[1],
            (const float*)out, 0, big, MQKV, Mrows, 2304, 768);
        attn_mfma_ker<<<dim3(Hc, Bc, 2), 256, 0, stream>>>(big, MQKV, tbuf, MC);
        gemm64_bf16_ker<2, float><<<dim3(6, 98, 2), 256, 0, stream>>>(
            tbuf, MC, wT + OFF_PROJ, WSTREAM, projb[0], projb[1],
            (const float*)out, MC, out, MC, Mrows, 768, 768);
        ln_ker<<<dim3(Mrows, 1, 2), 256, 0, stream>>>(
            out, MC, g2[0], b2[0], g2[1], b2[1], tbuf, MC);
        gemm_bf16_ker<1, __hip_bfloat16><<<dim3(24, 49, 2), 256, 0, stream>>>(
            tbuf, MC, wT + OFF_FC1, WSTREAM, fc1b[0], fc1b[1],
            (const float*)out, 0, big, MFF, Mrows, 3072, 768);
        gemm64_bf16_ker<2, float><<<dim3(6, 98, 2), 256, 0, stream>>>(
            big, MFF, wT + OFF_FC2, WSTREAM, fc2b[0], fc2b[1],
            (const float*)out, MC, out, MC, Mrows, 768, 3072);
    } else {
        inject_ker<<<2 * Mrows, 256, 0, stream>>>(x, y, fusedb, scale_a, scale_v, out);
        wcast_all_ker<<<dim3(6912, 1, 2), 256, 0, stream>>>(wa);
        for (int p = 0; p < 2; ++p) {
            float* X = out + (size_t)p * MC;
            __hip_bfloat16* wb = wT + p * WSTREAM;
            ln_ker<<<dim3(Mrows, 1, 1), 256, 0, stream>>>(
                X, 0, g1[p], b1[p], g1[p], b1[p], tbuf, 0);
            gemm_bf16_ker<0, __hip_bfloat16><<<dim3(18, 49, 1), 256, 0, stream>>>(
                tbuf, 0, wb + OFF_QKV, 0, qkvb[p], qkvb[p],
                (const float*)X, 0, big, 0, Mrows, 2304, 768);
            attn_mfma_ker<<<dim3(Hc, Bc, 1), 256, 0, stream>>>(big, 0, tbuf, 0);
            gemm64_bf16_ker<2, float><<<dim3(6, 98, 1), 256, 0, stream>>>(
                tbuf, 0, wb + OFF_PROJ, 0, projb[p], projb[p],
                (const float*)X, 0, X, 0, Mrows, 768, 768);
            ln_ker<<<dim3(Mrows, 1, 1), 256, 0, stream>>>(
                X, 0, g2[p], b2[p], g2[p], b2[p], tbuf, 0);
            gemm_bf16_ker<1, __hip_bfloat16><<<dim3(24, 49, 1), 256, 0, stream>>>(
                tbuf, 0, wb + OFF_FC1, 0, fc1b[p], fc1b[p],
                (const float*)X, 0, big, 0, Mrows, 3072, 768);
            gemm64_bf16_ker<2, float><<<dim3(6, 98, 1), 256, 0, stream>>>(
                big, 0, wb + OFF_FC2, 0, fc2b[p], fc2b[p],
                (const float*)X, 0, X, 0, Mrows, 768, 3072);
        }
    }
}

// Round 15
// 397.222 us; speedup vs baseline: 1.0127x; 1.0127x over previous
//
#include <hip/hip_runtime.h>
#include <hip/hip_bf16.h>
#include <math.h>

// ---- problem constants ----
constexpr int Bc   = 32;
constexpr int Nc   = 196;
constexpr int Cc   = 768;
constexpr int Hc   = 12;
constexpr int HDc  = 64;
constexpr int Lc   = 4;
constexpr int DFFc = 3072;
constexpr int NCAT = 2 * Nc;          // 392
constexpr int Mrows = Bc * Nc;        // 6272
constexpr float SCALE_C = 0.03608439182435161f;  // 768^-0.5
constexpr float SCALE_H = 0.125f;                // 64^-0.5
constexpr float LOG2E   = 1.4426950408889634f;

typedef __attribute__((ext_vector_type(8))) short short8;
typedef __attribute__((ext_vector_type(4))) short s16x4;
typedef __attribute__((ext_vector_type(4))) float float4a;
typedef __attribute__((ext_vector_type(4))) _Float16 half4;

// tanh-form GELU (max |err| vs exact ~1e-3; margin is 0.086)
__device__ inline float gelu_fast(float v) {
    float c = v * (0.7978845608028654f + 0.035677408136300125f * v * v);
    float ex = __expf(2.f * c);
    float th = 1.f - 2.f / (ex + 1.f);
    return 0.5f * v * (1.f + th);
}

__device__ inline void store_val(float* p, float v) { *p = v; }
__device__ inline void store_val(__hip_bfloat16* p, float v) { *p = __float2bfloat16(v); }

__device__ inline void gload16(const void* g, void* l) {
    __builtin_amdgcn_global_load_lds(
        (const __attribute__((address_space(1))) void*)g,
        (__attribute__((address_space(3))) void*)l, 16, 0, 0);
}

// =====================================================================
// Latent scores: one WAVE per (b,j), all 4 latents at once.
// =====================================================================
__global__ __launch_bounds__(256) void lat_scores_ker(
    const float* __restrict__ x, const float* __restrict__ y,
    const float* __restrict__ lat, float* __restrict__ scores)
{
    int wglobal = blockIdx.x * 4 + (threadIdx.x >> 6);
    int lane = threadIdx.x & 63;
    int b = wglobal / NCAT, j = wglobal % NCAT;
    const float* row = (j < Nc) ? x + ((size_t)b * Nc + j) * Cc
                                : y + ((size_t)b * Nc + (j - Nc)) * Cc;
    float a0 = 0.f, a1 = 0.f, a2 = 0.f, a3 = 0.f;
    for (int c = lane; c < Cc; c += 64) {
        float rv = row[c];
        a0 += rv * lat[c];
        a1 += rv * lat[Cc + c];
        a2 += rv * lat[2 * Cc + c];
        a3 += rv * lat[3 * Cc + c];
    }
    #pragma unroll
    for (int o = 32; o; o >>= 1) {
        a0 += __shfl_xor(a0, o);
        a1 += __shfl_xor(a1, o);
        a2 += __shfl_xor(a2, o);
        a3 += __shfl_xor(a3, o);
    }
    if (lane == 0) {
        float* sb = scores + (size_t)b * Lc * NCAT + j;
        sb[0 * NCAT] = a0 * SCALE_C;
        sb[1 * NCAT] = a1 * SCALE_C;
        sb[2 * NCAT] = a2 * SCALE_C;
        sb[3 * NCAT] = a3 * SCALE_C;
    }
}

// =====================================================================
// softmax(scores) (in-LDS, wave w -> latent w) + fused = probs @ concat.
// grid (Bc, 12): 64-col chunk.
// =====================================================================
__global__ __launch_bounds__(256) void lat_fused_ker(
    const float* __restrict__ x, const float* __restrict__ y,
    const float* __restrict__ scores, float* __restrict__ fused)
{
    int b = blockIdx.x, chunk = blockIdx.y;
    int t = threadIdx.x;
    __shared__ float p[Lc][NCAT];
    for (int idx = t; idx < Lc * NCAT; idx += 256)
        (&p[0][0])[idx] = scores[(size_t)b * Lc * NCAT + idx];
    __syncthreads();
    int w = t >> 6, lane = t & 63;
    {   // wave w softmaxes latent row w (redundant across chunks; cheap)
        float m = -INFINITY;
        for (int j = lane; j < NCAT; j += 64) m = fmaxf(m, p[w][j]);
        #pragma unroll
        for (int o = 32; o; o >>= 1) m = fmaxf(m, __shfl_xor(m, o));
        float sum = 0.f;
        for (int j = lane; j < NCAT; j += 64) {
            float e = expf(p[w][j] - m);
            p[w][j] = e;
            sum += e;
        }
        #pragma unroll
        for (int o = 32; o; o >>= 1) sum += __shfl_xor(sum, o);
        float inv = 1.f / sum;
        for (int j = lane; j < NCAT; j += 64) p[w][j] *= inv;
    }
    __syncthreads();

    int l = w;
    int c = chunk * 64 + lane;
    float acc0 = 0.f, acc1 = 0.f;
    for (int j = 0; j < Nc; j += 2) {
        const float* r0 = x + ((size_t)b * Nc + j) * Cc;
        acc0 += p[l][j] * r0[c];
        acc1 += p[l][j + 1] * r0[Cc + c];
    }
    for (int j = 0; j < Nc; j += 2) {
        const float* r0 = y + ((size_t)b * Nc + j) * Cc;
        acc0 += p[l][Nc + j] * r0[c];
        acc1 += p[l][Nc + j + 1] * r0[Cc + c];
    }
    fused[(size_t)b * Lc * Cc + l * Cc + c] = acc0 + acc1;
}

// =====================================================================
// inject (fallback, no LN): out = src + scale * sdpa(src, fused, fused)
// =====================================================================
__global__ __launch_bounds__(256) void inject_ker(
    const float* __restrict__ x, const float* __restrict__ y,
    const float* __restrict__ fused,
    const float* __restrict__ scale_a, const float* __restrict__ scale_v,
    float* __restrict__ out)
{
    int gid = blockIdx.x;
    int st = gid / Mrows;
    int bn = gid % Mrows;
    int b = bn / Nc;
    const float* src = st ? y : x;
    float scale = st ? scale_v[0] : scale_a[0];
    float* dst = out + (size_t)st * Mrows * Cc;
    const float* f = fused + (size_t)b * Lc * Cc;
    const float* row = src + (size_t)bn * Cc;

    __shared__ float sc[4];
    int w = threadIdx.x >> 6, lane = threadIdx.x & 63;
    float partial = 0.f;
    for (int c = lane; c < Cc; c += 64) partial += row[c] * f[w * Cc + c];
    #pragma unroll
    for (int o = 32; o; o >>= 1) partial += __shfl_xor(partial, o);
    if (lane == 0) sc[w] = partial * SCALE_C;
    __syncthreads();

    float s0 = sc[0], s1 = sc[1], s2 = sc[2], s3 = sc[3];
    float m = fmaxf(fmaxf(s0, s1), fmaxf(s2, s3));
    float e0 = expf(s0 - m), e1 = expf(s1 - m), e2 = expf(s2 - m), e3 = expf(s3 - m);
    float inv = 1.f / (e0 + e1 + e2 + e3);
    e0 *= inv; e1 *= inv; e2 *= inv; e3 *= inv;

    for (int c = threadIdx.x; c < Cc; c += 256) {
        float v = e0 * f[c] + e1 * f[Cc + c] + e2 * f[2 * Cc + c] + e3 * f[3 * Cc + c];
        dst[(size_t)bn * Cc + c] = row[c] + scale * v;
    }
}

// =====================================================================
// inject + LN1 fused: u = src + scale*sdpa; out=u (fp32); lnout=LN(u) bf16
// =====================================================================
__global__ __launch_bounds__(256) void inject_ln_ker(
    const float* __restrict__ x, const float* __restrict__ y,
    const float* __restrict__ fusedb,
    const float* __restrict__ scale_a, const float* __restrict__ scale_v,
    const float* __restrict__ ga, const float* __restrict__ ba,
    const float* __restrict__ gv, const float* __restrict__ bv,
    float* __restrict__ out, __hip_bfloat16* __restrict__ lnout, size_t lnz)
{
    int gid = blockIdx.x;
    int st = gid / Mrows;
    int bn = gid % Mrows;
    int b = bn / Nc;
    const float* src = st ? y : x;
    float scale = st ? scale_v[0] : scale_a[0];
    const float* g  = st ? gv : ga;
    const float* bb = st ? bv : ba;
    float* dst = out + (size_t)st * Mrows * Cc + (size_t)bn * Cc;
    __hip_bfloat16* lno = lnout + (size_t)st * lnz + (size_t)bn * Cc;
    const float* f = fusedb + (size_t)b * Lc * Cc;
    const float* row = src + (size_t)bn * Cc;

    __shared__ float sc[4];
    __shared__ float red[4];
    int t = threadIdx.x;
    int w = t >> 6, lane = t & 63;
    float partial = 0.f;
    for (int c = lane; c < Cc; c += 64) partial += row[c] * f[w * Cc + c];
    #pragma unroll
    for (int o = 32; o; o >>= 1) partial += __shfl_xor(partial, o);
    if (lane == 0) sc[w] = partial * SCALE_C;
    __syncthreads();

    float s0 = sc[0], s1 = sc[1], s2 = sc[2], s3 = sc[3];
    float m = fmaxf(fmaxf(s0, s1), fmaxf(s2, s3));
    float e0 = expf(s0 - m), e1 = expf(s1 - m), e2 = expf(s2 - m), e3 = expf(s3 - m);
    float inv = 1.f / (e0 + e1 + e2 + e3);
    e0 *= inv; e1 *= inv; e2 *= inv; e3 *= inv;

    float u[3];
    float s = 0.f;
    #pragma unroll
    for (int k = 0; k < 3; ++k) {
        int c = t + 256 * k;
        float v = e0 * f[c] + e1 * f[Cc + c] + e2 * f[2 * Cc + c] + e3 * f[3 * Cc + c];
        u[k] = row[c] + scale * v;
        s += u[k];
    }
    #pragma unroll
    for (int o = 32; o; o >>= 1) s += __shfl_xor(s, o);
    if (lane == 0) red[w] = s;
    __syncthreads();
    float mean = (red[0] + red[1] + red[2] + red[3]) * (1.f / Cc);

    float vs = 0.f;
    #pragma unroll
    for (int k = 0; k < 3; ++k) { float d = u[k] - mean; vs += d * d; }
    #pragma unroll
    for (int o = 32; o; o >>= 1) vs += __shfl_xor(vs, o);
    __syncthreads();
    if (lane == 0) red[w] = vs;
    __syncthreads();
    float var = (red[0] + red[1] + red[2] + red[3]) * (1.f / Cc);
    float rinv = 1.f / sqrtf(var + 1e-6f);

    #pragma unroll
    for (int k = 0; k < 3; ++k) {
        int c = t + 256 * k;
        dst[c] = u[k];
        lno[c] = __float2bfloat16((u[k] - mean) * rinv * g[c] + bb[c]);
    }
}

// =====================================================================
// LayerNorm -> bf16, float4-vectorized, values kept in registers.
// =====================================================================
__global__ __launch_bounds__(256) void ln_ker(
    const float* __restrict__ in, size_t inz,
    const float* __restrict__ g0, const float* __restrict__ b0,
    const float* __restrict__ g1, const float* __restrict__ b1,
    __hip_bfloat16* __restrict__ out, size_t outz)
{
    int z = blockIdx.z;
    const float* g = z ? g1 : g0;
    const float* bb = z ? b1 : b0;
    in += (size_t)z * inz; out += (size_t)z * outz;

    int row = blockIdx.x;
    __shared__ float red[4];
    __shared__ float red2[4];
    const float* r = in + (size_t)row * Cc;
    int t = threadIdx.x;
    int w = t >> 6, lane = t & 63;
    bool act = t < 192;

    float4 v = act ? *reinterpret_cast<const float4*>(r + t * 4)
                   : make_float4(0.f, 0.f, 0.f, 0.f);
    float s = v.x + v.y + v.z + v.w;
    #pragma unroll
    for (int o = 32; o; o >>= 1) s += __shfl_xor(s, o);
    if (lane == 0) red[w] = s;
    __syncthreads();
    float mean = (red[0] + red[1] + red[2] + red[3]) * (1.f / Cc);

    float d0 = v.x - mean, d1 = v.y - mean, d2 = v.z - mean, d3 = v.w - mean;
    float vs = act ? (d0 * d0 + d1 * d1 + d2 * d2 + d3 * d3) : 0.f;
    #pragma unroll
    for (int o = 32; o; o >>= 1) vs += __shfl_xor(vs, o);
    if (lane == 0) red2[w] = vs;
    __syncthreads();
    float var = (red2[0] + red2[1] + red2[2] + red2[3]) * (1.f / Cc);
    float inv = 1.f / sqrtf(var + 1e-6f);

    if (act) {
        float4 gv = *reinterpret_cast<const float4*>(g + t * 4);
        float4 bv = *reinterpret_cast<const float4*>(bb + t * 4);
        __hip_bfloat16 tmp[4];
        tmp[0] = __float2bfloat16(d0 * inv * gv.x + bv.x);
        tmp[1] = __float2bfloat16(d1 * inv * gv.y + bv.y);
        tmp[2] = __float2bfloat16(d2 * inv * gv.z + bv.z);
        tmp[3] = __float2bfloat16(d3 * inv * gv.w + bv.w);
        *reinterpret_cast<s16x4*>(out + (size_t)row * Cc + t * 4) =
            *reinterpret_cast<const s16x4*>(tmp);
    }
}

// =====================================================================
// All 8 weight transposes, float4-vectorized. grid (6912, 1, 2).
// =====================================================================
struct WArgs {
    const float* src[8];
    __hip_bfloat16* dst[8];
};

__global__ __launch_bounds__(256) void wcast_all_ker(WArgs wa)
{
    int z = blockIdx.z;
    int bx = blockIdx.x;
    int which, tile, K_, N_;
    if (bx < 1728)      { which = 0; tile = bx;        K_ = 768;  N_ = 2304; }
    else if (bx < 2304) { which = 1; tile = bx - 1728; K_ = 768;  N_ = 768;  }
    else if (bx < 4608) { which = 2; tile = bx - 2304; K_ = 768;  N_ = 3072; }
    else                { which = 3; tile = bx - 4608; K_ = 3072; N_ = 768;  }
    const float* W = wa.src[z * 4 + which];
    __hip_bfloat16* WT = wa.dst[z * 4 + which];
    int ntx = N_ >> 5;
    int n0 = (tile % ntx) * 32, k0 = (tile / ntx) * 32;

    __shared__ float tilebuf[32][33];
    int t = threadIdx.x;
    int r = t >> 3, c4 = (t & 7) * 4;
    float4 v = *reinterpret_cast<const float4*>(&W[(size_t)(k0 + r) * N_ + n0 + c4]);
    tilebuf[r][c4 + 0] = v.x;
    tilebuf[r][c4 + 1] = v.y;
    tilebuf[r][c4 + 2] = v.z;
    tilebuf[r][c4 + 3] = v.w;
    __syncthreads();

    int rn = t >> 3, k4 = (t & 7) * 4;
    __hip_bfloat16 tmp[4];
    #pragma unroll
    for (int i = 0; i < 4; ++i)
        tmp[i] = __float2bfloat16(tilebuf[k4 + i][rn]);
    *reinterpret_cast<s16x4*>(&WT[(size_t)(n0 + rn) * K_ + k0 + k4]) =
        *reinterpret_cast<const s16x4*>(tmp);
}

// =====================================================================
// bf16 MFMA GEMM, 128x128 tile: BK=64 single-buffered (32 KB LDS),
// two __syncthreads per K-tile, (256,2), XCD-chunk swizzle, fast GELU.
// Empirical optimum across 6 tested structural variants (r5,r8,r9,r12,r14).
// =====================================================================
template <int EPI, typename OutT>
__global__ __launch_bounds__(256, 2) void gemm_bf16_ker(
    const __hip_bfloat16* __restrict__ A, size_t Az,
    const __hip_bfloat16* __restrict__ BT, size_t BTz,
    const float* __restrict__ bias0, const float* __restrict__ bias1,
    const float* __restrict__ res, size_t resz,
    OutT* __restrict__ out, size_t outz,
    int M_, int N_, int K_)
{
    const int gx = gridDim.x, gy = gridDim.y;
    const long T = (long)gx * gy * gridDim.z;
    long iflat = blockIdx.x + (long)gx * (blockIdx.y + (long)gy * blockIdx.z);
    long q = T >> 3, r = T & 7;
    long xcd = iflat & 7, jj = iflat >> 3;
    long tt = (xcd < r ? xcd * (q + 1) : r * (q + 1) + (xcd - r) * q) + jj;
    const int bx = (int)(tt % gx);
    const int by = (int)((tt / gx) % gy);
    const int z  = (int)(tt / ((long)gx * gy));

    A += (size_t)z * Az;
    BT += (size_t)z * BTz;
    const float* bias = z ? bias1 : bias0;
    res += (size_t)z * resz;
    out += (size_t)z * outz;

    __shared__ short As[128 * 64];
    __shared__ short Bs[128 * 64];
    const int t = threadIdx.x;
    const int wid = t >> 6, lane = t & 63;
    const int row0 = by * 128, col0 = bx * 128;
    const int wr = (wid >> 1) * 64, wc = (wid & 1) * 64;

    const __hip_bfloat16* aSrc[4];
    const __hip_bfloat16* bSrc[4];
    int ldsOff[4];
    #pragma unroll
    for (int ii = 0; ii < 4; ++ii) {
        int f = wid * 1024 + ii * 4096 + lane * 16;
        int rw = f >> 7;
        int us = ((f >> 4) & 7) ^ (rw & 7);
        aSrc[ii] = A + (size_t)(row0 + rw) * K_ + us * 8;
        bSrc[ii] = BT + (size_t)(col0 + rw) * K_ + us * 8;
        ldsOff[ii] = (wid * 1024 + ii * 4096) >> 1;
    }

    const int fr = lane & 15;
    const int ku = lane >> 4;
    int rlA[4], rlB[4];
    #pragma unroll
    for (int m = 0; m < 4; ++m) {
        rlA[m] = wr + m * 16 + fr;
        rlB[m] = wc + m * 16 + fr;
    }

    float4a acc[4][4];
    #pragma unroll
    for (int m = 0; m < 4; ++m)
        #pragma unroll
        for (int n = 0; n < 4; ++n)
            acc[m][n] = (float4a)0.f;

    for (int kt = 0; kt < K_; kt += 64) {
        #pragma unroll
        for (int ii = 0; ii < 4; ++ii) {
            gload16(aSrc[ii] + kt, As + ldsOff[ii]);
            gload16(bSrc[ii] + kt, Bs + ldsOff[ii]);
        }
        __syncthreads();

        #pragma unroll
        for (int s = 0; s < 2; ++s) {
            short8 af[4], bf8[4];
            #pragma unroll
            for (int m = 0; m < 4; ++m) {
                int u = (s * 4 + ku) ^ (rlA[m] & 7);
                af[m] = *(const short8*)(As + rlA[m] * 64 + u * 8);
            }
            #pragma unroll
            for (int n = 0; n < 4; ++n) {
                int u = (s * 4 + ku) ^ (rlB[n] & 7);
                bf8[n] = *(const short8*)(Bs + rlB[n] * 64 + u * 8);
            }
            #pragma unroll
            for (int m = 0; m < 4; ++m)
                #pragma unroll
                for (int n = 0; n < 4; ++n)
                    acc[m][n] = __builtin_amdgcn_mfma_f32_16x16x32_bf16(
                        af[m], bf8[n], acc[m][n], 0, 0, 0);
        }
        __syncthreads();
    }

    const int fq = lane >> 4;
    #pragma unroll
    for (int m = 0; m < 4; ++m) {
        #pragma unroll
        for (int n = 0; n < 4; ++n) {
            int col = col0 + wc + n * 16 + fr;
            float b = bias[col];
            #pragma unroll
            for (int j = 0; j < 4; ++j) {
                int row = row0 + wr + m * 16 + fq * 4 + j;
                float v = acc[m][n][j] + b;
                if (EPI == 1) v = gelu_fast(v);
                if (EPI == 2) v += res[(size_t)row * N_ + col];
                store_val(out + (size_t)row * N_ + col, v);
            }
        }
    }
}

// =====================================================================
// MFMA attention, z-batched. Block per (h, b, z).
// =====================================================================
constexpr int NKT = 13;
constexpr int NQT = 13;
constexpr int NPAD = NKT * 16;   // 208
constexpr int VTS = 216;

__global__ __launch_bounds__(256) void attn_mfma_ker(
    const __hip_bfloat16* __restrict__ qkv, size_t qz,
    __hip_bfloat16* __restrict__ o, size_t oz)
{
    int z = blockIdx.z;
    qkv += (size_t)z * qz;
    o += (size_t)z * oz;

    int h = blockIdx.x, b = blockIdx.y;
    __shared__ short Ks[NPAD * 64];
    __shared__ _Float16 VT[64 * VTS];
    const size_t rs = 3 * Cc;
    const __hip_bfloat16* base = qkv + (size_t)b * Nc * rs + h * HDc;
    const int t = threadIdx.x;

    for (int c = t; c < NPAD * 8; c += 256) {
        int row = c >> 3, u = c & 7;
        int srow = row < Nc ? row : Nc - 1;
        short8 kv = *(const short8*)(base + (size_t)srow * rs + Cc + u * 8);
        *(short8*)(Ks + row * 64 + ((u ^ (row & 7)) << 3)) = kv;
        short8 vv = *(const short8*)(base + (size_t)srow * rs + 2 * Cc + u * 8);
        #pragma unroll
        for (int w = 0; w < 8; ++w) {
            __hip_bfloat16 bvv = ((const __hip_bfloat16*)&vv)[w];
            VT[(u * 8 + w) * VTS + row] = (_Float16)__bfloat162float(bvv);
        }
    }
    __syncthreads();

    const int wv = t >> 6, lane = t & 63;
    const int g = lane >> 4, c16 = lane & 15;
    const float KS = SCALE_H * LOG2E;

    for (int qt = wv; qt < NQT; qt += 4) {
        int qrow = qt * 16 + c16;
        int sq = qrow < Nc ? qrow : Nc - 1;
        const __hip_bfloat16* qb = base + (size_t)sq * rs + g * 8;
        short8 bq0 = *(const short8*)(qb);
        short8 bq1 = *(const short8*)(qb + 32);

        float4a acc[NKT];
        #pragma unroll
        for (int kt = 0; kt < NKT; ++kt) acc[kt] = (float4a)0.f;
        #pragma unroll
        for (int kt = 0; kt < NKT; ++kt) {
            int r = kt * 16 + c16;
            short8 a0 = *(const short8*)(Ks + r * 64 + ((g ^ (r & 7)) << 3));
            short8 a1 = *(const short8*)(Ks + r * 64 + (((4 + g) ^ (r & 7)) << 3));
            acc[kt] = __builtin_amdgcn_mfma_f32_16x16x32_bf16(a0, bq0, acc[kt], 0, 0, 0);
            acc[kt] = __builtin_amdgcn_mfma_f32_16x16x32_bf16(a1, bq1, acc[kt], 0, 0, 0);
        }

        float m = -INFINITY;
        #pragma unroll
        for (int kt = 0; kt < NKT; ++kt) {
            #pragma unroll
            for (int j = 0; j < 4; ++j) {
                int key = kt * 16 + g * 4 + j;
                float v = (key < Nc) ? acc[kt][j] * KS : -INFINITY;
                acc[kt][j] = v;
                m = fmaxf(m, v);
            }
        }
        m = fmaxf(m, __shfl_xor(m, 16));
        m = fmaxf(m, __shfl_xor(m, 32));

        float sum = 0.f;
        half4 pb[NKT];
        #pragma unroll
        for (int kt = 0; kt < NKT; ++kt) {
            #pragma unroll
            for (int j = 0; j < 4; ++j) {
                float e = exp2f(acc[kt][j] - m);
                sum += e;
                pb[kt][j] = (_Float16)e;
            }
        }
        sum += __shfl_xor(sum, 16);
        sum += __shfl_xor(sum, 32);
        float inv = 1.f / sum;

        float4a oa[4];
        #pragma unroll
        for (int dt = 0; dt < 4; ++dt) oa[dt] = (float4a)0.f;
        #pragma unroll
        for (int kt = 0; kt < NKT; ++kt) {
            #pragma unroll
            for (int dt = 0; dt < 4; ++dt) {
                half4 av = *(const half4*)(VT + (size_t)(dt * 16 + c16) * VTS
                                              + kt * 16 + g * 4);
                oa[dt] = __builtin_amdgcn_mfma_f32_16x16x16f16(av, pb[kt], oa[dt], 0, 0, 0);
            }
        }

        if (qrow < Nc) {
            __hip_bfloat16* ob = o + ((size_t)b * Nc + qrow) * Cc + h * HDc;
            #pragma unroll
            for (int dt = 0; dt < 4; ++dt) {
                __hip_bfloat16 tmp[4];
                #pragma unroll
                for (int j = 0; j < 4; ++j)
                    tmp[j] = __float2bfloat16(oa[dt][j] * inv);
                *(s16x4*)(ob + dt * 16 + g * 4) = *(const s16x4*)tmp;
            }
        }
    }
}

// =====================================================================
extern "C" void kernel_launch(void* const* d_in, const int* in_sizes, int n_in,
                              void* d_out, int out_size, void* d_ws, size_t ws_size,
                              hipStream_t stream)
{
    const float* x       = (const float*)d_in[0];
    const float* y       = (const float*)d_in[1];
    const float* latents = (const float*)d_in[2];
    const float* scale_a = (const float*)d_in[3];
    const float* scale_v = (const float*)d_in[4];

    float* out = (float*)d_out;

    constexpr size_t WSTREAM = 7077888;
    constexpr size_t OFF_QKV = 0;
    constexpr size_t OFF_PROJ = 2304 * 768;
    constexpr size_t OFF_FC1 = OFF_PROJ + 768 * 768;
    constexpr size_t OFF_FC2 = OFF_FC1 + 3072 * 768;

    constexpr size_t FRONT = ((size_t)Bc * Lc * NCAT + (size_t)Bc * Lc * Cc) * 4;
    constexpr size_t NEED_BATCH = FRONT
        + 2 * (size_t)Mrows * Cc * 2
        + 2 * (size_t)Mrows * DFFc * 2
        + 2 * WSTREAM * 2;

    float* ws = (float*)d_ws;
    float* scores = ws;
    float* fusedb = scores + (size_t)Bc * Lc * NCAT;

    const bool batched = ws_size >= NEED_BATCH;

    __hip_bfloat16* tbuf = (__hip_bfloat16*)(fusedb + (size_t)Bc * Lc * Cc);
    __hip_bfloat16* big;
    __hip_bfloat16* wT;
    if (batched) {
        big = tbuf + 2 * (size_t)Mrows * Cc;
        wT  = big + 2 * (size_t)Mrows * DFFc;
    } else {
        big = tbuf + (size_t)Mrows * Cc;
        wT  = big + (size_t)Mrows * DFFc;
    }

    // ---- latent bottleneck fusion ----
    lat_scores_ker<<<Bc * NCAT / 4, 256, 0, stream>>>(x, y, latents, scores);
    lat_fused_ker<<<dim3(Bc, 12), 256, 0, stream>>>(x, y, scores, fusedb);

    // ---- weight cast+transpose (all 8 at once) ----
    WArgs wa;
    for (int p = 0; p < 2; ++p) {
        int basei = 5 + 12 * p;
        wa.src[p * 4 + 0] = (const float*)d_in[basei + 2];
        wa.src[p * 4 + 1] = (const float*)d_in[basei + 4];
        wa.src[p * 4 + 2] = (const float*)d_in[basei + 8];
        wa.src[p * 4 + 3] = (const float*)d_in[basei + 10];
        wa.dst[p * 4 + 0] = wT + p * WSTREAM + OFF_QKV;
        wa.dst[p * 4 + 1] = wT + p * WSTREAM + OFF_PROJ;
        wa.dst[p * 4 + 2] = wT + p * WSTREAM + OFF_FC1;
        wa.dst[p * 4 + 3] = wT + p * WSTREAM + OFF_FC2;
    }

    const float* g1[2], *b1[2], *qkvb[2], *projb[2], *g2[2], *b2[2], *fc1b[2], *fc2b[2];
    for (int p = 0; p < 2; ++p) {
        int basei = 5 + 12 * p;
        g1[p]    = (const float*)d_in[basei + 0];
        b1[p]    = (const float*)d_in[basei + 1];
        qkvb[p]  = (const float*)d_in[basei + 3];
        projb[p] = (const float*)d_in[basei + 5];
        g2[p]    = (const float*)d_in[basei + 6];
        b2[p]    = (const float*)d_in[basei + 7];
        fc1b[p]  = (const float*)d_in[basei + 9];
        fc2b[p]  = (const float*)d_in[basei + 11];
    }

    const size_t MC = (size_t)Mrows * Cc;
    const size_t MQKV = (size_t)Mrows * 2304;
    const size_t MFF = (size_t)Mrows * DFFc;

    if (batched) {
        inject_ln_ker<<<2 * Mrows, 256, 0, stream>>>(
            x, y, fusedb, scale_a, scale_v,
            g1[0], b1[0], g1[1], b1[1], out, tbuf, MC);
        wcast_all_ker<<<dim3(6912, 1, 2), 256, 0, stream>>>(wa);
        gemm_bf16_ker<0, __hip_bfloat16><<<dim3(18, 49, 2), 256, 0, stream>>>(
            tbuf, MC, wT + OFF_QKV, WSTREAM, qkvb[0], qkvb[1],
            (const float*)out, 0, big, MQKV, Mrows, 2304, 768);
        attn_mfma_ker<<<dim3(Hc, Bc, 2), 256, 0, stream>>>(big, MQKV, tbuf, MC);
        gemm_bf16_ker<2, float><<<dim3(6, 49, 2), 256, 0, stream>>>(
            tbuf, MC, wT + OFF_PROJ, WSTREAM, projb[0], projb[1],
            (const float*)out, MC, out, MC, Mrows, 768, 768);
        ln_ker<<<dim3(Mrows, 1, 2), 256, 0, stream>>>(
            out, MC, g2[0], b2[0], g2[1], b2[1], tbuf, MC);
        gemm_bf16_ker<1, __hip_bfloat16><<<dim3(24, 49, 2), 256, 0, stream>>>(
            tbuf, MC, wT + OFF_FC1, WSTREAM, fc1b[0], fc1b[1],
            (const float*)out, 0, big, MFF, Mrows, 3072, 768);
        gemm_bf16_ker<2, float><<<dim3(6, 49, 2), 256, 0, stream>>>(
            big, MFF, wT + OFF_FC2, WSTREAM, fc2b[0], fc2b[1],
            (const float*)out, MC, out, MC, Mrows, 768, 3072);
    } else {
        inject_ker<<<2 * Mrows, 256, 0, stream>>>(x, y, fusedb, scale_a, scale_v, out);
        wcast_all_ker<<<dim3(6912, 1, 2), 256, 0, stream>>>(wa);
        for (int p = 0; p < 2; ++p) {
            float* X = out + (size_t)p * MC;
            __hip_bfloat16* wb = wT + p * WSTREAM;
            ln_ker<<<dim3(Mrows, 1, 1), 256, 0, stream>>>(
                X, 0, g1[p], b1[p], g1[p], b1[p], tbuf, 0);
            gemm_bf16_ker<0, __hip_bfloat16><<<dim3(18, 49, 1), 256, 0, stream>>>(
                tbuf, 0, wb + OFF_QKV, 0, qkvb[p], qkvb[p],
                (const float*)X, 0, big, 0, Mrows, 2304, 768);
            attn_mfma_ker<<<dim3(Hc, Bc, 1), 256, 0, stream>>>(big, 0, tbuf, 0);
            gemm_bf16_ker<2, float><<<dim3(6, 49, 1), 256, 0, stream>>>(
                tbuf, 0, wb + OFF_PROJ, 0, projb[p], projb[p],
                (const float*)X, 0, X, 0, Mrows, 768, 768);
            ln_ker<<<dim3(Mrows, 1, 1), 256, 0, stream>>>(
                X, 0, g2[p], b2[p], g2[p], b2[p], tbuf, 0);
            gemm_bf16_ker<1, __hip_bfloat16><<<dim3(24, 49, 1), 256, 0, stream>>>(
                tbuf, 0, wb + OFF_FC1, 0, fc1b[p], fc1b[p],
                (const float*)X, 0, big, 0, Mrows, 3072, 768);
            gemm_bf16_ker<2, float><<<dim3(6, 49, 1), 256, 0, stream>>>(
                big, 0, wb + OFF_FC2, 0, fc2b[p], fc2b[p],
                (const float*)X, 0, X, 0, Mrows, 768, 3072);
        }
    }
}